// Round 5
// baseline (437.190 us; speedup 1.0000x reference)
//
// GLM4 attention block (B=1, L=2048, HID=4096, H=32, KV=2, D=128, ROT=64) on MI355X.
// Round 5: GEMM 256x128xBK32, 4 waves, 3-buffer LDS, counted vmcnt(6) pipeline
//   (2 tiles in flight, single barrier/iter, no drain-to-0 in main loop),
//   QKV output stored bf16. Attn unchanged (round-3 structure).
#include <hip/hip_runtime.h>
#include <stdint.h>

#define L_SEQ 2048
#define HID   4096
#define NH    32
#define NKV   2
#define DH    128
#define NQKV  4608                     // H*D + 2*KV*D
#define QSCALE 0.088388347648318447f   // 128^-0.5

typedef __bf16 bf16x8 __attribute__((ext_vector_type(8)));
typedef float  f32x4  __attribute__((ext_vector_type(4)));

__device__ __forceinline__ unsigned short f2bf(float f) {
  union { float f; unsigned u; } cv; cv.f = f;
  unsigned u = cv.u;
  return (unsigned short)((u + 0x7fffu + ((u >> 16) & 1u)) >> 16);   // RNE, finite-only
}
__device__ __forceinline__ float bf2f(unsigned short h) {
  union { unsigned u; float f; } cv; cv.u = (unsigned)h << 16; return cv.f;
}

// async global->LDS, 16B per lane; LDS dest = wave-uniform base + lane*16
#define GLL16(gsrc, ldst)                                                              \
  __builtin_amdgcn_global_load_lds(                                                    \
      (const __attribute__((address_space(1))) unsigned int*)(gsrc),                   \
      (__attribute__((address_space(3))) unsigned int*)(ldst), 16, 0, 0)

// ---------------------------------------------------------------- casts
__global__ __launch_bounds__(256) void cast_bf16_kernel(const float* __restrict__ in,
                                                        unsigned short* __restrict__ out,
                                                        int n4) {
  int i = blockIdx.x * 256 + threadIdx.x;
  if (i >= n4) return;
  float4 v = reinterpret_cast<const float4*>(in)[i];
  ushort4 o;
  o.x = f2bf(v.x); o.y = f2bf(v.y); o.z = f2bf(v.z); o.w = f2bf(v.w);
  reinterpret_cast<ushort4*>(out)[i] = o;
}

// in: (R,C) fp32 row-major -> out: (C,R) bf16 row-major
__global__ __launch_bounds__(256) void transpose_cast_kernel(const float* __restrict__ in,
                                                             unsigned short* __restrict__ out,
                                                             int R, int C) {
  __shared__ float tile[32][33];
  int c0 = blockIdx.x * 32, r0 = blockIdx.y * 32;
  int tx = threadIdx.x, ty = threadIdx.y;
  #pragma unroll
  for (int i = ty; i < 32; i += 8)
    tile[i][tx] = in[(size_t)(r0 + i) * C + (c0 + tx)];
  __syncthreads();
  #pragma unroll
  for (int i = ty; i < 32; i += 8)
    out[(size_t)(c0 + i) * R + (r0 + tx)] = f2bf(tile[tx][i]);
}

// ---------------------------------------------------------------- GEMM  C(M,N) = A(M,K) * Bt(N,K)^T
// BM=256, BN=128, BK=32; 4 waves, wave-tile 128x64 (8x4 16x16 frags);
// 3-buffer swizzled LDS, counted vmcnt(6) 2-deep pipeline, 1 barrier/iter.
#define GBM 256
#define GBN 128
#define GBK 32

template <int OUT_BF16>
__global__ __launch_bounds__(256, 2) void gemm256_kernel(const unsigned short* __restrict__ A,
                                                         const unsigned short* __restrict__ Bt,
                                                         void* __restrict__ Cv,
                                                         int M, int N, int K) {
  __shared__ __attribute__((aligned(16))) unsigned short As[3][GBM * GBK];
  __shared__ __attribute__((aligned(16))) unsigned short Bs[3][GBN * GBK];
  const int tid = threadIdx.x;
  const int wave = tid >> 6, lane = tid & 63;
  const int lg = lane >> 4, ll = lane & 15;
  const int wm = wave >> 1, wn = wave & 1;     // 2x2 wave grid, 128x64 each

  // XCD-chunked block swizzle (bijective when nwg%8==0)
  int gx = gridDim.x, nwg = gx * gridDim.y;
  int flat = blockIdx.y * gx + blockIdx.x;
  int bx = blockIdx.x, by = blockIdx.y;
  if ((nwg & 7) == 0) {
    int t = (flat & 7) * (nwg >> 3) + (flat >> 3);
    bx = t % gx; by = t / gx;
  }
  const int m0 = by * GBM, n0 = bx * GBN;

  f32x4 acc[8][4] = {};
  const int NT = K >> 5;   // K / 32  (>= 2 always here)

  // swz(row) = (row ^ (row>>2)) & 3 ; physical chunk p holds global chunk p^swz(row)
  auto stage = [&](int t, int buf) {
    const int k0 = t * GBK;
    #pragma unroll
    for (int i = 0; i < 4; ++i) {
      int ci  = (wave * 4 + i) * 64 + lane;
      int row = ci >> 2;
      int cg  = (ci & 3) ^ ((row ^ (row >> 2)) & 3);
      GLL16(A + (size_t)(m0 + row) * K + k0 + cg * 8, &As[buf][(wave * 4 + i) * 512]);
    }
    #pragma unroll
    for (int i = 0; i < 2; ++i) {
      int ci  = (wave * 2 + i) * 64 + lane;
      int row = ci >> 2;
      int cg  = (ci & 3) ^ ((row ^ (row >> 2)) & 3);
      GLL16(Bt + (size_t)(n0 + row) * K + k0 + cg * 8, &Bs[buf][(wave * 2 + i) * 512]);
    }
  };

  auto compute = [&](int buf) {
    const unsigned short* Ac = &As[buf][0];
    const unsigned short* Bc = &Bs[buf][0];
    bf16x8 bfr[4], afr[8];
    #pragma unroll
    for (int j = 0; j < 4; ++j) {
      int row = wn * 64 + j * 16 + ll;
      bfr[j] = *reinterpret_cast<const bf16x8*>(
          &Bc[row * 32 + ((lg ^ ((row ^ (row >> 2)) & 3)) * 8)]);
    }
    #pragma unroll
    for (int i = 0; i < 8; ++i) {
      int row = wm * 128 + i * 16 + ll;
      afr[i] = *reinterpret_cast<const bf16x8*>(
          &Ac[row * 32 + ((lg ^ ((row ^ (row >> 2)) & 3)) * 8)]);
    }
    __builtin_amdgcn_s_setprio(1);
    #pragma unroll
    for (int i = 0; i < 8; ++i)
      #pragma unroll
      for (int j = 0; j < 4; ++j)
        acc[i][j] = __builtin_amdgcn_mfma_f32_16x16x32_bf16(afr[i], bfr[j], acc[i][j], 0, 0, 0);
    __builtin_amdgcn_s_setprio(0);
  };

  stage(0, 0);
  stage(1, 1);

  int cur = 0;
  for (int t = 0; t < NT - 1; ++t) {
    // tile t's 6 loads are the oldest; allow stage(t+1)'s 6 to stay in flight
    asm volatile("s_waitcnt vmcnt(6)" ::: "memory");
    __builtin_amdgcn_s_barrier();
    asm volatile("" ::: "memory");
    if (t + 2 < NT) {
      int nb = cur + 2; if (nb >= 3) nb -= 3;
      stage(t + 2, nb);
    }
    compute(cur);
    ++cur; if (cur >= 3) cur = 0;
  }
  // peeled final iteration: drain
  asm volatile("s_waitcnt vmcnt(0)" ::: "memory");
  __builtin_amdgcn_s_barrier();
  asm volatile("" ::: "memory");
  compute(cur);

  #pragma unroll
  for (int i = 0; i < 8; ++i)
    #pragma unroll
    for (int j = 0; j < 4; ++j) {
      int col  = n0 + wn * 64 + j * 16 + ll;
      int rowb = m0 + wm * 128 + i * 16 + lg * 4;
      #pragma unroll
      for (int r = 0; r < 4; ++r) {
        size_t idx = (size_t)(rowb + r) * N + col;
        if (OUT_BF16) ((unsigned short*)Cv)[idx] = f2bf(acc[i][j][r]);
        else          ((float*)Cv)[idx]          = acc[i][j][r];
      }
    }
}

// ---------------------------------------------------------------- bias + RoPE + relayout
// qkv: [L][4608] bf16. cols 0..4095 = Q, 4096..4351 = K, 4352..4607 = V.
__global__ __launch_bounds__(128) void rope_q_kernel(const unsigned short* __restrict__ qkv,
                                                     const float* __restrict__ bq,
                                                     const float* __restrict__ cosT,
                                                     const float* __restrict__ sinT,
                                                     unsigned short* __restrict__ qb) {
  int l = blockIdx.x, h = blockIdx.y, d = threadIdx.x;
  size_t base = (size_t)l * NQKV + h * DH;
  float v = bf2f(qkv[base + d]) + bq[h * DH + d];
  float o;
  if (d < 32) {
    float x2 = bf2f(qkv[base + d + 32]) + bq[h * DH + d + 32];
    o = v * cosT[l * 32 + d] - x2 * sinT[l * 32 + d];
  } else if (d < 64) {
    int i = d - 32;
    float x1 = bf2f(qkv[base + i]) + bq[h * DH + i];
    o = v * cosT[l * 32 + i] + x1 * sinT[l * 32 + i];
  } else {
    o = v;
  }
  qb[((size_t)h * L_SEQ + l) * DH + d] = f2bf(o * QSCALE);
}

__global__ __launch_bounds__(128) void rope_k_kernel(const unsigned short* __restrict__ qkv,
                                                     const float* __restrict__ bk,
                                                     const float* __restrict__ cosT,
                                                     const float* __restrict__ sinT,
                                                     unsigned short* __restrict__ kb) {
  int l = blockIdx.x, g = blockIdx.y, d = threadIdx.x;
  size_t base = (size_t)l * NQKV + 4096 + g * DH;
  float v = bf2f(qkv[base + d]) + bk[g * DH + d];
  float o;
  if (d < 32) {
    float x2 = bf2f(qkv[base + d + 32]) + bk[g * DH + d + 32];
    o = v * cosT[l * 32 + d] - x2 * sinT[l * 32 + d];
  } else if (d < 64) {
    int i = d - 32;
    float x1 = bf2f(qkv[base + i]) + bk[g * DH + i];
    o = v * cosT[l * 32 + i] + x1 * sinT[l * 32 + i];
  } else {
    o = v;
  }
  kb[((size_t)g * L_SEQ + l) * DH + d] = f2bf(o);
}

// V stored transposed: vt[g][d][l]
__global__ __launch_bounds__(128) void bias_vt_kernel(const unsigned short* __restrict__ qkv,
                                                      const float* __restrict__ bv,
                                                      unsigned short* __restrict__ vt) {
  int l = blockIdx.x, g = blockIdx.y, d = threadIdx.x;
  float o = bf2f(qkv[(size_t)l * NQKV + 4352 + g * DH + d]) + bv[g * DH + d];
  vt[((size_t)g * DH + d) * L_SEQ + l] = f2bf(o);
}

// ---------------------------------------------------------------- flash attention
// grid (16, H); 256 threads = 4 waves. Causal fold-pairing: block pair p handles
// q-tiles p and 31-p (QB=64) sequentially -> uniform 33 KV-tiles per block.
__device__ __forceinline__ int p_addr(int row, int chunk) {
  return row * 72 + (((chunk + row + (row >> 2)) & 7) * 8);
}

__global__ __launch_bounds__(256) void attn_kernel(const unsigned short* __restrict__ qg,
                                                   const unsigned short* __restrict__ kb,
                                                   const unsigned short* __restrict__ vt,
                                                   unsigned short* __restrict__ ob) {
  __shared__ __attribute__((aligned(16))) unsigned short Ks[2][64 * 128];
  __shared__ __attribute__((aligned(16))) unsigned short Vs[2][128 * 64];
  __shared__ __attribute__((aligned(16))) unsigned short Ps[4][16 * 72];

  const int pair = blockIdx.x, h = blockIdx.y;
  const int g = h >> 4;                         // 16 q-heads per kv-head
  const int tid = threadIdx.x, wave = tid >> 6, lane = tid & 63;
  const int lg = lane >> 4, ll = lane & 15;

  const int krow = (lane >> 4);
  const int kcg0 = (lane & 15);
  const int vrow = (lane >> 3);
  const int vcg0 = (lane & 7);

  #pragma unroll
  for (int seg = 0; seg < 2; ++seg) {
    const int qt = seg ? (31 - pair) : pair;
    const int q0 = qt * 64 + wave * 16;

    bf16x8 qf[4];
    #pragma unroll
    for (int f = 0; f < 4; ++f)
      qf[f] = *reinterpret_cast<const bf16x8*>(
          qg + ((size_t)h * L_SEQ + q0 + ll) * DH + f * 32 + lg * 8);

    f32x4 of[8] = {};
    float m[4]  = {-1e30f, -1e30f, -1e30f, -1e30f};
    float lsum[4] = {0.f, 0.f, 0.f, 0.f};

    const int kvN = qt + 1;
    int cur = 0;

    #pragma unroll
    for (int c = 0; c < 4; ++c) {
      int issue = wave * 4 + c;
      int rk = issue * 4 + krow;
      GLL16(kb + ((size_t)g * L_SEQ + rk) * DH + (kcg0 ^ (rk & 7)) * 8, &Ks[0][issue * 512]);
      int rv = issue * 8 + vrow;
      GLL16(vt + ((size_t)g * DH + rv) * L_SEQ + (vcg0 ^ (rv & 7)) * 8, &Vs[0][issue * 512]);
    }
    __syncthreads();

    for (int t = 0; t < kvN; ++t) {
      if (t + 1 < kvN) {
        int kv1 = (t + 1) * 64;
        #pragma unroll
        for (int c = 0; c < 4; ++c) {
          int issue = wave * 4 + c;
          int rk = issue * 4 + krow;
          GLL16(kb + ((size_t)g * L_SEQ + kv1 + rk) * DH + (kcg0 ^ (rk & 7)) * 8,
                &Ks[cur ^ 1][issue * 512]);
          int rv = issue * 8 + vrow;
          GLL16(vt + ((size_t)g * DH + rv) * L_SEQ + kv1 + (vcg0 ^ (rv & 7)) * 8,
                &Vs[cur ^ 1][issue * 512]);
        }
      }

      f32x4 s[4] = {};
      const unsigned short* Kc = &Ks[cur][0];
      #pragma unroll
      for (int cf = 0; cf < 4; ++cf) {
        bf16x8 kf[4];
        #pragma unroll
        for (int f = 0; f < 4; ++f) {
          int rk = cf * 16 + ll;
          int cc = (f * 4 + lg) ^ (rk & 7);
          kf[f] = *reinterpret_cast<const bf16x8*>(&Kc[rk * 128 + cc * 8]);
        }
        __builtin_amdgcn_s_setprio(1);
        #pragma unroll
        for (int f = 0; f < 4; ++f)
          s[cf] = __builtin_amdgcn_mfma_f32_16x16x32_bf16(qf[f], kf[f], s[cf], 0, 0, 0);
        __builtin_amdgcn_s_setprio(0);
      }

      if (t == qt) {
        #pragma unroll
        for (int cf = 0; cf < 4; ++cf)
          #pragma unroll
          for (int r = 0; r < 4; ++r)
            if (cf * 16 + ll > wave * 16 + lg * 4 + r) s[cf][r] = -1e30f;
      }

      float pmax[4];
      #pragma unroll
      for (int r = 0; r < 4; ++r)
        pmax[r] = fmaxf(fmaxf(s[0][r], s[1][r]), fmaxf(s[2][r], s[3][r]));
      bool ok = true;
      #pragma unroll
      for (int r = 0; r < 4; ++r) ok = ok && (pmax[r] - m[r] <= 8.f);
      if (!__all(ok)) {
        float alpha[4];
        #pragma unroll
        for (int r = 0; r < 4; ++r) {
          float mx = pmax[r];
          #pragma unroll
          for (int msk = 1; msk < 16; msk <<= 1) mx = fmaxf(mx, __shfl_xor(mx, msk));
          float mnew = fmaxf(m[r], mx);
          alpha[r] = __expf(m[r] - mnew);
          m[r] = mnew;
          lsum[r] *= alpha[r];
        }
        #pragma unroll
        for (int ds = 0; ds < 8; ++ds)
          #pragma unroll
          for (int r = 0; r < 4; ++r)
            of[ds][r] *= alpha[r];
      }
      #pragma unroll
      for (int cf = 0; cf < 4; ++cf)
        #pragma unroll
        for (int r = 0; r < 4; ++r) {
          s[cf][r] = __expf(s[cf][r] - m[r]);
          lsum[r] += s[cf][r];
        }

      unsigned short* pw = &Ps[wave][0];
      #pragma unroll
      for (int cf = 0; cf < 4; ++cf)
        #pragma unroll
        for (int r = 0; r < 4; ++r) {
          int rr = lg * 4 + r;
          int c  = cf * 16 + ll;
          pw[p_addr(rr, c >> 3) + (c & 7)] = f2bf(s[cf][r]);
        }
      bf16x8 pa[2];
      #pragma unroll
      for (int ks = 0; ks < 2; ++ks)
        pa[ks] = *reinterpret_cast<const bf16x8*>(&pw[p_addr(ll, ks * 4 + lg)]);

      const unsigned short* Vc = &Vs[cur][0];
      #pragma unroll
      for (int ds = 0; ds < 8; ++ds) {
        bf16x8 vf[2];
        #pragma unroll
        for (int ks = 0; ks < 2; ++ks) {
          int dl = ds * 16 + ll;
          int cc = (ks * 4 + lg) ^ (dl & 7);
          vf[ks] = *reinterpret_cast<const bf16x8*>(&Vc[dl * 64 + cc * 8]);
        }
        __builtin_amdgcn_s_setprio(1);
        #pragma unroll
        for (int ks = 0; ks < 2; ++ks)
          of[ds] = __builtin_amdgcn_mfma_f32_16x16x32_bf16(pa[ks], vf[ks], of[ds], 0, 0, 0);
        __builtin_amdgcn_s_setprio(0);
      }

      __syncthreads();
      cur ^= 1;
    }

    float inv[4];
    #pragma unroll
    for (int r = 0; r < 4; ++r) {
      float sum = lsum[r];
      #pragma unroll
      for (int msk = 1; msk < 16; msk <<= 1) sum += __shfl_xor(sum, msk);
      inv[r] = 1.f / sum;
    }
    #pragma unroll
    for (int ds = 0; ds < 8; ++ds)
      #pragma unroll
      for (int r = 0; r < 4; ++r) {
        int row = q0 + lg * 4 + r;
        ob[(size_t)row * (NH * DH) + h * DH + ds * 16 + ll] = f2bf(of[ds][r] * inv[r]);
      }
    __syncthreads();
  }
}

// ---------------------------------------------------------------- launch
extern "C" void kernel_launch(void* const* d_in, const int* in_sizes, int n_in,
                              void* d_out, int out_size, void* d_ws, size_t ws_size,
                              hipStream_t stream) {
  (void)in_sizes; (void)n_in; (void)out_size; (void)ws_size;
  const float* x    = (const float*)d_in[0];
  const float* Wq   = (const float*)d_in[1];
  const float* bq   = (const float*)d_in[2];
  const float* Wk   = (const float*)d_in[3];
  const float* bk   = (const float*)d_in[4];
  const float* Wv   = (const float*)d_in[5];
  const float* bv   = (const float*)d_in[6];
  const float* Wo   = (const float*)d_in[7];
  const float* cosT = (const float*)d_in[8];
  const float* sinT = (const float*)d_in[9];
  // d_in[10] = attention_mask: unused (causal mask computed arithmetically)

  char* ws = (char*)d_ws;
  size_t off = 0;
  auto alloc = [&](size_t bytes) { void* p = ws + off; off += (bytes + 255) & ~(size_t)255; return p; };
  unsigned short* xb     = (unsigned short*)alloc((size_t)L_SEQ * HID * 2);
  unsigned short* Wqkvt  = (unsigned short*)alloc((size_t)NQKV * HID * 2);
  unsigned short* Wot    = (unsigned short*)alloc((size_t)HID * HID * 2);
  unsigned short* qkvlin = (unsigned short*)alloc((size_t)L_SEQ * NQKV * 2);     // bf16 now
  unsigned short* qbuf   = (unsigned short*)alloc((size_t)NH * L_SEQ * DH * 2);
  unsigned short* kbuf   = (unsigned short*)alloc((size_t)NKV * L_SEQ * DH * 2);
  unsigned short* vtb    = (unsigned short*)alloc((size_t)NKV * DH * L_SEQ * 2);
  unsigned short* attno  = (unsigned short*)alloc((size_t)L_SEQ * HID * 2);      // attn out bf16

  cast_bf16_kernel<<<(L_SEQ * HID / 4 + 255) / 256, 256, 0, stream>>>(x, xb, L_SEQ * HID / 4);
  transpose_cast_kernel<<<dim3(HID / 32, HID / 32), dim3(32, 8), 0, stream>>>(Wq, Wqkvt, HID, HID);
  transpose_cast_kernel<<<dim3(256 / 32, HID / 32), dim3(32, 8), 0, stream>>>(Wk, Wqkvt + (size_t)4096 * HID, HID, 256);
  transpose_cast_kernel<<<dim3(256 / 32, HID / 32), dim3(32, 8), 0, stream>>>(Wv, Wqkvt + (size_t)4352 * HID, HID, 256);
  transpose_cast_kernel<<<dim3(HID / 32, HID / 32), dim3(32, 8), 0, stream>>>(Wo, Wot, HID, HID);

  gemm256_kernel<1><<<dim3(NQKV / GBN, L_SEQ / GBM), 256, 0, stream>>>(xb, Wqkvt, qkvlin, L_SEQ, NQKV, HID);

  rope_q_kernel<<<dim3(L_SEQ, NH), 128, 0, stream>>>(qkvlin, bq, cosT, sinT, qbuf);
  rope_k_kernel<<<dim3(L_SEQ, NKV), 128, 0, stream>>>(qkvlin, bk, cosT, sinT, kbuf);
  bias_vt_kernel<<<dim3(L_SEQ, NKV), 128, 0, stream>>>(qkvlin, bv, vtb);

  attn_kernel<<<dim3(16, NH), 256, 0, stream>>>(qbuf, kbuf, vtb, attno);

  gemm256_kernel<0><<<dim3(HID / GBN, L_SEQ / GBM), 256, 0, stream>>>(attno, Wot, (float*)d_out, L_SEQ, HID, HID);
}

// Round 6
// 363.804 us; speedup vs baseline: 1.2017x; 1.2017x over previous
//
// GLM4 attention block (B=1, L=2048, HID=4096, H=32, KV=2, D=128, ROT=64) on MI355X.
// Round 6: GEMM back to 128x128 (BK=64), 4 waves, 2-buffer LDS = 64KB -> 2 blocks/CU
//   co-resident; counted vmcnt(8) pipeline (stage t+2 after lgkm-drain barrier);
//   8-chunk XOR swizzle. Rope/bias merged into one kernel. Attn unchanged.
#include <hip/hip_runtime.h>
#include <stdint.h>

#define L_SEQ 2048
#define HID   4096
#define NH    32
#define NKV   2
#define DH    128
#define NQKV  4608                     // H*D + 2*KV*D
#define QSCALE 0.088388347648318447f   // 128^-0.5

typedef __bf16 bf16x8 __attribute__((ext_vector_type(8)));
typedef float  f32x4  __attribute__((ext_vector_type(4)));

__device__ __forceinline__ unsigned short f2bf(float f) {
  union { float f; unsigned u; } cv; cv.f = f;
  unsigned u = cv.u;
  return (unsigned short)((u + 0x7fffu + ((u >> 16) & 1u)) >> 16);   // RNE, finite-only
}
__device__ __forceinline__ float bf2f(unsigned short h) {
  union { unsigned u; float f; } cv; cv.u = (unsigned)h << 16; return cv.f;
}

// async global->LDS, 16B per lane; LDS dest = wave-uniform base + lane*16
#define GLL16(gsrc, ldst)                                                              \
  __builtin_amdgcn_global_load_lds(                                                    \
      (const __attribute__((address_space(1))) unsigned int*)(gsrc),                   \
      (__attribute__((address_space(3))) unsigned int*)(ldst), 16, 0, 0)

// ---------------------------------------------------------------- casts
__global__ __launch_bounds__(256) void cast_bf16_kernel(const float* __restrict__ in,
                                                        unsigned short* __restrict__ out,
                                                        int n4) {
  int i = blockIdx.x * 256 + threadIdx.x;
  if (i >= n4) return;
  float4 v = reinterpret_cast<const float4*>(in)[i];
  ushort4 o;
  o.x = f2bf(v.x); o.y = f2bf(v.y); o.z = f2bf(v.z); o.w = f2bf(v.w);
  reinterpret_cast<ushort4*>(out)[i] = o;
}

// in: (R,C) fp32 row-major -> out: (C,R) bf16 row-major
__global__ __launch_bounds__(256) void transpose_cast_kernel(const float* __restrict__ in,
                                                             unsigned short* __restrict__ out,
                                                             int R, int C) {
  __shared__ float tile[32][33];
  int c0 = blockIdx.x * 32, r0 = blockIdx.y * 32;
  int tx = threadIdx.x, ty = threadIdx.y;
  #pragma unroll
  for (int i = ty; i < 32; i += 8)
    tile[i][tx] = in[(size_t)(r0 + i) * C + (c0 + tx)];
  __syncthreads();
  #pragma unroll
  for (int i = ty; i < 32; i += 8)
    out[(size_t)(c0 + i) * R + (r0 + tx)] = f2bf(tile[tx][i]);
}

// ---------------------------------------------------------------- GEMM  C(M,N) = A(M,K) * Bt(N,K)^T
// BM=BN=128, BK=64; 4 waves, wave-tile 64x64 (4x4 16x16 frags);
// 2-buffer LDS (64KB -> 2 blocks/CU), counted vmcnt(8), stage(t+2) after
// lgkm-drain barrier. Row = 8 chunks of 16B; physical chunk p = c ^ (row&7).
#define TBM 128
#define TBN 128
#define TBK 64

template <int OUT_BF16>
__global__ __launch_bounds__(256, 2) void gemm128_kernel(const unsigned short* __restrict__ A,
                                                         const unsigned short* __restrict__ Bt,
                                                         void* __restrict__ Cv,
                                                         int M, int N, int K) {
  __shared__ __attribute__((aligned(16))) unsigned short As[2][TBM * TBK];
  __shared__ __attribute__((aligned(16))) unsigned short Bs[2][TBN * TBK];
  const int tid = threadIdx.x;
  const int wave = tid >> 6, lane = tid & 63;
  const int lg = lane >> 4, ll = lane & 15;
  const int wm = wave >> 1, wn = wave & 1;     // 2x2 wave grid, 64x64 each

  // XCD-chunked block swizzle (bijective when nwg%8==0)
  int gx = gridDim.x, nwg = gx * gridDim.y;
  int flat = blockIdx.y * gx + blockIdx.x;
  int bx = blockIdx.x, by = blockIdx.y;
  if ((nwg & 7) == 0) {
    int t = (flat & 7) * (nwg >> 3) + (flat >> 3);
    bx = t % gx; by = t / gx;
  }
  const int m0 = by * TBM, n0 = bx * TBN;

  f32x4 acc[4][4] = {};
  const int NT = K >> 6;   // K/64, >= 2 here

  // tile = 128 rows x 8 chunks(16B) = 1024 chunks; each wave-issue covers 64.
  auto stage = [&](int t, int buf) {
    const int k0 = t * TBK;
    #pragma unroll
    for (int i = 0; i < 4; ++i) {
      int ci  = (i * 4 + wave) * 64 + lane;
      int row = ci >> 3;
      int cg  = (ci & 7) ^ (row & 7);
      GLL16(A + (size_t)(m0 + row) * K + k0 + cg * 8, &As[buf][(i * 4 + wave) * 512]);
    }
    #pragma unroll
    for (int i = 0; i < 4; ++i) {
      int ci  = (i * 4 + wave) * 64 + lane;
      int row = ci >> 3;
      int cg  = (ci & 7) ^ (row & 7);
      GLL16(Bt + (size_t)(n0 + row) * K + k0 + cg * 8, &Bs[buf][(i * 4 + wave) * 512]);
    }
  };

  stage(0, 0);
  stage(1, 1);

  for (int t = 0; t < NT; ++t) {
    const int cur = t & 1;
    // tile t's 8 loads are the oldest; stage(t+1)'s 8 may stay in flight
    if (t + 1 < NT) asm volatile("s_waitcnt vmcnt(8)" ::: "memory");
    else            asm volatile("s_waitcnt vmcnt(0)" ::: "memory");
    __builtin_amdgcn_s_barrier();      // buf cur visible to all waves

    const unsigned short* Ac = &As[cur][0];
    const unsigned short* Bc = &Bs[cur][0];
    bf16x8 afr[2][4], bfr[2][4];
    #pragma unroll
    for (int kk = 0; kk < 2; ++kk)
      #pragma unroll
      for (int i = 0; i < 4; ++i) {
        int ra = wm * 64 + i * 16 + ll;
        afr[kk][i] = *reinterpret_cast<const bf16x8*>(
            &Ac[ra * 64 + (((kk * 4 + lg) ^ (ra & 7)) * 8)]);
        int rb = wn * 64 + i * 16 + ll;
        bfr[kk][i] = *reinterpret_cast<const bf16x8*>(
            &Bc[rb * 64 + (((kk * 4 + lg) ^ (rb & 7)) * 8)]);
      }
    asm volatile("s_waitcnt lgkmcnt(0)" ::: "memory");
    __builtin_amdgcn_s_barrier();      // all waves done reading buf cur
    if (t + 2 < NT) stage(t + 2, cur); // refill the vacated buffer

    __builtin_amdgcn_s_setprio(1);
    #pragma unroll
    for (int kk = 0; kk < 2; ++kk)
      #pragma unroll
      for (int i = 0; i < 4; ++i)
        #pragma unroll
        for (int j = 0; j < 4; ++j)
          acc[i][j] = __builtin_amdgcn_mfma_f32_16x16x32_bf16(afr[kk][i], bfr[kk][j],
                                                              acc[i][j], 0, 0, 0);
    __builtin_amdgcn_s_setprio(0);
  }

  #pragma unroll
  for (int i = 0; i < 4; ++i)
    #pragma unroll
    for (int j = 0; j < 4; ++j) {
      int col  = n0 + wn * 64 + j * 16 + ll;
      int rowb = m0 + wm * 64 + i * 16 + lg * 4;
      #pragma unroll
      for (int r = 0; r < 4; ++r) {
        size_t idx = (size_t)(rowb + r) * N + col;
        if (OUT_BF16) ((unsigned short*)Cv)[idx] = f2bf(acc[i][j][r]);
        else          ((float*)Cv)[idx]          = acc[i][j][r];
      }
    }
}

// ---------------------------------------------------------------- bias + RoPE + relayout (merged)
// qkv: [L][4608] bf16. cols 0..4095 = Q, 4096..4351 = K, 4352..4607 = V.
// grid (L, 36): y<32 -> Q head y ; y in {32,33} -> K g=y-32 ; y in {34,35} -> V g=y-34.
__global__ __launch_bounds__(128) void qkv_post_kernel(const unsigned short* __restrict__ qkv,
                                                       const float* __restrict__ bq,
                                                       const float* __restrict__ bk,
                                                       const float* __restrict__ bv,
                                                       const float* __restrict__ cosT,
                                                       const float* __restrict__ sinT,
                                                       unsigned short* __restrict__ qb,
                                                       unsigned short* __restrict__ kb,
                                                       unsigned short* __restrict__ vt) {
  int l = blockIdx.x, y = blockIdx.y, d = threadIdx.x;
  if (y < 34) {                                 // Q or K: bias + RoPE
    const bool isq = (y < 32);
    const int hh = isq ? y : (y - 32);
    const float* bias = isq ? bq : bk;
    size_t base = (size_t)l * NQKV + (isq ? 0 : 4096) + hh * DH;
    float v = bf2f(qkv[base + d]) + bias[hh * DH + d];
    float o;
    if (d < 32) {
      float x2 = bf2f(qkv[base + d + 32]) + bias[hh * DH + d + 32];
      o = v * cosT[l * 32 + d] - x2 * sinT[l * 32 + d];
    } else if (d < 64) {
      int i = d - 32;
      float x1 = bf2f(qkv[base + i]) + bias[hh * DH + i];
      o = v * cosT[l * 32 + i] + x1 * sinT[l * 32 + i];
    } else {
      o = v;
    }
    if (isq) qb[((size_t)hh * L_SEQ + l) * DH + d] = f2bf(o * QSCALE);
    else     kb[((size_t)hh * L_SEQ + l) * DH + d] = f2bf(o);
  } else {                                      // V: bias, stored transposed vt[g][d][l]
    int g = y - 34;
    float o = bf2f(qkv[(size_t)l * NQKV + 4352 + g * DH + d]) + bv[g * DH + d];
    vt[((size_t)g * DH + d) * L_SEQ + l] = f2bf(o);
  }
}

// ---------------------------------------------------------------- flash attention
// grid (16, H); 256 threads = 4 waves. Causal fold-pairing: block pair p handles
// q-tiles p and 31-p (QB=64) sequentially -> uniform 33 KV-tiles per block.
__device__ __forceinline__ int p_addr(int row, int chunk) {
  return row * 72 + (((chunk + row + (row >> 2)) & 7) * 8);
}

__global__ __launch_bounds__(256) void attn_kernel(const unsigned short* __restrict__ qg,
                                                   const unsigned short* __restrict__ kb,
                                                   const unsigned short* __restrict__ vt,
                                                   unsigned short* __restrict__ ob) {
  __shared__ __attribute__((aligned(16))) unsigned short Ks[2][64 * 128];
  __shared__ __attribute__((aligned(16))) unsigned short Vs[2][128 * 64];
  __shared__ __attribute__((aligned(16))) unsigned short Ps[4][16 * 72];

  const int pair = blockIdx.x, h = blockIdx.y;
  const int g = h >> 4;                         // 16 q-heads per kv-head
  const int tid = threadIdx.x, wave = tid >> 6, lane = tid & 63;
  const int lg = lane >> 4, ll = lane & 15;

  const int krow = (lane >> 4);
  const int kcg0 = (lane & 15);
  const int vrow = (lane >> 3);
  const int vcg0 = (lane & 7);

  #pragma unroll
  for (int seg = 0; seg < 2; ++seg) {
    const int qt = seg ? (31 - pair) : pair;
    const int q0 = qt * 64 + wave * 16;

    bf16x8 qf[4];
    #pragma unroll
    for (int f = 0; f < 4; ++f)
      qf[f] = *reinterpret_cast<const bf16x8*>(
          qg + ((size_t)h * L_SEQ + q0 + ll) * DH + f * 32 + lg * 8);

    f32x4 of[8] = {};
    float m[4]  = {-1e30f, -1e30f, -1e30f, -1e30f};
    float lsum[4] = {0.f, 0.f, 0.f, 0.f};

    const int kvN = qt + 1;
    int cur = 0;

    #pragma unroll
    for (int c = 0; c < 4; ++c) {
      int issue = wave * 4 + c;
      int rk = issue * 4 + krow;
      GLL16(kb + ((size_t)g * L_SEQ + rk) * DH + (kcg0 ^ (rk & 7)) * 8, &Ks[0][issue * 512]);
      int rv = issue * 8 + vrow;
      GLL16(vt + ((size_t)g * DH + rv) * L_SEQ + (vcg0 ^ (rv & 7)) * 8, &Vs[0][issue * 512]);
    }
    __syncthreads();

    for (int t = 0; t < kvN; ++t) {
      if (t + 1 < kvN) {
        int kv1 = (t + 1) * 64;
        #pragma unroll
        for (int c = 0; c < 4; ++c) {
          int issue = wave * 4 + c;
          int rk = issue * 4 + krow;
          GLL16(kb + ((size_t)g * L_SEQ + kv1 + rk) * DH + (kcg0 ^ (rk & 7)) * 8,
                &Ks[cur ^ 1][issue * 512]);
          int rv = issue * 8 + vrow;
          GLL16(vt + ((size_t)g * DH + rv) * L_SEQ + kv1 + (vcg0 ^ (rv & 7)) * 8,
                &Vs[cur ^ 1][issue * 512]);
        }
      }

      f32x4 s[4] = {};
      const unsigned short* Kc = &Ks[cur][0];
      #pragma unroll
      for (int cf = 0; cf < 4; ++cf) {
        bf16x8 kf[4];
        #pragma unroll
        for (int f = 0; f < 4; ++f) {
          int rk = cf * 16 + ll;
          int cc = (f * 4 + lg) ^ (rk & 7);
          kf[f] = *reinterpret_cast<const bf16x8*>(&Kc[rk * 128 + cc * 8]);
        }
        __builtin_amdgcn_s_setprio(1);
        #pragma unroll
        for (int f = 0; f < 4; ++f)
          s[cf] = __builtin_amdgcn_mfma_f32_16x16x32_bf16(qf[f], kf[f], s[cf], 0, 0, 0);
        __builtin_amdgcn_s_setprio(0);
      }

      if (t == qt) {
        #pragma unroll
        for (int cf = 0; cf < 4; ++cf)
          #pragma unroll
          for (int r = 0; r < 4; ++r)
            if (cf * 16 + ll > wave * 16 + lg * 4 + r) s[cf][r] = -1e30f;
      }

      float pmax[4];
      #pragma unroll
      for (int r = 0; r < 4; ++r)
        pmax[r] = fmaxf(fmaxf(s[0][r], s[1][r]), fmaxf(s[2][r], s[3][r]));
      bool ok = true;
      #pragma unroll
      for (int r = 0; r < 4; ++r) ok = ok && (pmax[r] - m[r] <= 8.f);
      if (!__all(ok)) {
        float alpha[4];
        #pragma unroll
        for (int r = 0; r < 4; ++r) {
          float mx = pmax[r];
          #pragma unroll
          for (int msk = 1; msk < 16; msk <<= 1) mx = fmaxf(mx, __shfl_xor(mx, msk));
          float mnew = fmaxf(m[r], mx);
          alpha[r] = __expf(m[r] - mnew);
          m[r] = mnew;
          lsum[r] *= alpha[r];
        }
        #pragma unroll
        for (int ds = 0; ds < 8; ++ds)
          #pragma unroll
          for (int r = 0; r < 4; ++r)
            of[ds][r] *= alpha[r];
      }
      #pragma unroll
      for (int cf = 0; cf < 4; ++cf)
        #pragma unroll
        for (int r = 0; r < 4; ++r) {
          s[cf][r] = __expf(s[cf][r] - m[r]);
          lsum[r] += s[cf][r];
        }

      unsigned short* pw = &Ps[wave][0];
      #pragma unroll
      for (int cf = 0; cf < 4; ++cf)
        #pragma unroll
        for (int r = 0; r < 4; ++r) {
          int rr = lg * 4 + r;
          int c  = cf * 16 + ll;
          pw[p_addr(rr, c >> 3) + (c & 7)] = f2bf(s[cf][r]);
        }
      bf16x8 pa[2];
      #pragma unroll
      for (int ks = 0; ks < 2; ++ks)
        pa[ks] = *reinterpret_cast<const bf16x8*>(&pw[p_addr(ll, ks * 4 + lg)]);

      const unsigned short* Vc = &Vs[cur][0];
      #pragma unroll
      for (int ds = 0; ds < 8; ++ds) {
        bf16x8 vf[2];
        #pragma unroll
        for (int ks = 0; ks < 2; ++ks) {
          int dl = ds * 16 + ll;
          int cc = (ks * 4 + lg) ^ (dl & 7);
          vf[ks] = *reinterpret_cast<const bf16x8*>(&Vc[dl * 64 + cc * 8]);
        }
        __builtin_amdgcn_s_setprio(1);
        #pragma unroll
        for (int ks = 0; ks < 2; ++ks)
          of[ds] = __builtin_amdgcn_mfma_f32_16x16x32_bf16(pa[ks], vf[ks], of[ds], 0, 0, 0);
        __builtin_amdgcn_s_setprio(0);
      }

      __syncthreads();
      cur ^= 1;
    }

    float inv[4];
    #pragma unroll
    for (int r = 0; r < 4; ++r) {
      float sum = lsum[r];
      #pragma unroll
      for (int msk = 1; msk < 16; msk <<= 1) sum += __shfl_xor(sum, msk);
      inv[r] = 1.f / sum;
    }
    #pragma unroll
    for (int ds = 0; ds < 8; ++ds)
      #pragma unroll
      for (int r = 0; r < 4; ++r) {
        int row = q0 + lg * 4 + r;
        ob[(size_t)row * (NH * DH) + h * DH + ds * 16 + ll] = f2bf(of[ds][r] * inv[r]);
      }
    __syncthreads();
  }
}

// ---------------------------------------------------------------- launch
extern "C" void kernel_launch(void* const* d_in, const int* in_sizes, int n_in,
                              void* d_out, int out_size, void* d_ws, size_t ws_size,
                              hipStream_t stream) {
  (void)in_sizes; (void)n_in; (void)out_size; (void)ws_size;
  const float* x    = (const float*)d_in[0];
  const float* Wq   = (const float*)d_in[1];
  const float* bq   = (const float*)d_in[2];
  const float* Wk   = (const float*)d_in[3];
  const float* bk   = (const float*)d_in[4];
  const float* Wv   = (const float*)d_in[5];
  const float* bv   = (const float*)d_in[6];
  const float* Wo   = (const float*)d_in[7];
  const float* cosT = (const float*)d_in[8];
  const float* sinT = (const float*)d_in[9];
  // d_in[10] = attention_mask: unused (causal mask computed arithmetically)

  char* ws = (char*)d_ws;
  size_t off = 0;
  auto alloc = [&](size_t bytes) { void* p = ws + off; off += (bytes + 255) & ~(size_t)255; return p; };
  unsigned short* xb     = (unsigned short*)alloc((size_t)L_SEQ * HID * 2);
  unsigned short* Wqkvt  = (unsigned short*)alloc((size_t)NQKV * HID * 2);
  unsigned short* Wot    = (unsigned short*)alloc((size_t)HID * HID * 2);
  unsigned short* qkvlin = (unsigned short*)alloc((size_t)L_SEQ * NQKV * 2);
  unsigned short* qbuf   = (unsigned short*)alloc((size_t)NH * L_SEQ * DH * 2);
  unsigned short* kbuf   = (unsigned short*)alloc((size_t)NKV * L_SEQ * DH * 2);
  unsigned short* vtb    = (unsigned short*)alloc((size_t)NKV * DH * L_SEQ * 2);
  unsigned short* attno  = (unsigned short*)alloc((size_t)L_SEQ * HID * 2);

  cast_bf16_kernel<<<(L_SEQ * HID / 4 + 255) / 256, 256, 0, stream>>>(x, xb, L_SEQ * HID / 4);
  transpose_cast_kernel<<<dim3(HID / 32, HID / 32), dim3(32, 8), 0, stream>>>(Wq, Wqkvt, HID, HID);
  transpose_cast_kernel<<<dim3(256 / 32, HID / 32), dim3(32, 8), 0, stream>>>(Wk, Wqkvt + (size_t)4096 * HID, HID, 256);
  transpose_cast_kernel<<<dim3(256 / 32, HID / 32), dim3(32, 8), 0, stream>>>(Wv, Wqkvt + (size_t)4352 * HID, HID, 256);
  transpose_cast_kernel<<<dim3(HID / 32, HID / 32), dim3(32, 8), 0, stream>>>(Wo, Wot, HID, HID);

  gemm128_kernel<1><<<dim3(NQKV / TBN, L_SEQ / TBM), 256, 0, stream>>>(xb, Wqkvt, qkvlin, L_SEQ, NQKV, HID);

  qkv_post_kernel<<<dim3(L_SEQ, 36), 128, 0, stream>>>(qkvlin, bq, bk, bv, cosT, sinT,
                                                       qbuf, kbuf, vtb);

  attn_kernel<<<dim3(16, NH), 256, 0, stream>>>(qbuf, kbuf, vtb, attno);

  gemm128_kernel<0><<<dim3(HID / TBN, L_SEQ / TBM), 256, 0, stream>>>(attno, Wot, (float*)d_out, L_SEQ, HID, HID);
}

// Round 7
// 352.742 us; speedup vs baseline: 1.2394x; 1.0314x over previous
//
// GLM4 attention block (B=1, L=2048, HID=4096, H=32, KV=2, D=128, ROT=64) on MI355X.
// Round 7: GEMM loop de-serialized (no lgkm(0) drain before MFMA; stage after 2nd
//   barrier). Attn: swapped QK^T (lane owns q-row) -> in-lane softmax, 4x ds_write_b64
//   P path. Transposes: 64x64 tiles, float4 loads, packed u32 writes.
#include <hip/hip_runtime.h>
#include <stdint.h>

#define L_SEQ 2048
#define HID   4096
#define NH    32
#define NKV   2
#define DH    128
#define NQKV  4608                     // H*D + 2*KV*D
#define QSCALE 0.088388347648318447f   // 128^-0.5

typedef __bf16 bf16x8 __attribute__((ext_vector_type(8)));
typedef float  f32x4  __attribute__((ext_vector_type(4)));

__device__ __forceinline__ unsigned short f2bf(float f) {
  union { float f; unsigned u; } cv; cv.f = f;
  unsigned u = cv.u;
  return (unsigned short)((u + 0x7fffu + ((u >> 16) & 1u)) >> 16);   // RNE, finite-only
}
__device__ __forceinline__ float bf2f(unsigned short h) {
  union { unsigned u; float f; } cv; cv.u = (unsigned)h << 16; return cv.f;
}

// async global->LDS, 16B per lane; LDS dest = wave-uniform base + lane*16
#define GLL16(gsrc, ldst)                                                              \
  __builtin_amdgcn_global_load_lds(                                                    \
      (const __attribute__((address_space(1))) unsigned int*)(gsrc),                   \
      (__attribute__((address_space(3))) unsigned int*)(ldst), 16, 0, 0)

// ---------------------------------------------------------------- casts
__global__ __launch_bounds__(256) void cast_bf16_kernel(const float* __restrict__ in,
                                                        unsigned short* __restrict__ out,
                                                        int n4) {
  int i = blockIdx.x * 256 + threadIdx.x;
  if (i >= n4) return;
  float4 v = reinterpret_cast<const float4*>(in)[i];
  ushort4 o;
  o.x = f2bf(v.x); o.y = f2bf(v.y); o.z = f2bf(v.z); o.w = f2bf(v.w);
  reinterpret_cast<ushort4*>(out)[i] = o;
}

// in: (R,C) fp32 row-major -> out: (C,R) bf16 row-major. 64x64 tiles, 256 threads.
__global__ __launch_bounds__(256) void transpose_cast_kernel(const float* __restrict__ in,
                                                             unsigned short* __restrict__ out,
                                                             int R, int C) {
  __shared__ float tile[64][65];
  const int c0 = blockIdx.x * 64, r0 = blockIdx.y * 64;
  const int tid = threadIdx.x;
  // load: 4 iters x 16 rows; each row = 16 float4 (64 floats)
  #pragma unroll
  for (int it = 0; it < 4; ++it) {
    int row = it * 16 + (tid >> 4);
    float4 v = *reinterpret_cast<const float4*>(&in[(size_t)(r0 + row) * C + c0 + (tid & 15) * 4]);
    tile[row][(tid & 15) * 4 + 0] = v.x;
    tile[row][(tid & 15) * 4 + 1] = v.y;
    tile[row][(tid & 15) * 4 + 2] = v.z;
    tile[row][(tid & 15) * 4 + 3] = v.w;
  }
  __syncthreads();
  // write: 8 iters x 8 c-rows; lane rp=tid&31 packs rows 2rp,2rp+1 into one u32
  #pragma unroll
  for (int it = 0; it < 8; ++it) {
    int c  = it * 8 + (tid >> 5);
    int rp = tid & 31;
    unsigned u = (unsigned)f2bf(tile[2 * rp][c]) | ((unsigned)f2bf(tile[2 * rp + 1][c]) << 16);
    *reinterpret_cast<unsigned*>(&out[(size_t)(c0 + c) * R + r0 + 2 * rp]) = u;
  }
}

// ---------------------------------------------------------------- GEMM  C(M,N) = A(M,K) * Bt(N,K)^T
// BM=BN=128, BK=64; 4 waves, wave-tile 64x64 (4x4 16x16 frags);
// 2-buffer LDS (64KB -> 2 blocks/CU), counted vmcnt(8).
// Iter: vmcnt -> bar -> 16 frag loads -> 32 MFMA (compiler lgkm interleave)
//       -> bar -> stage(t+2) into vacated buffer.
#define TBM 128
#define TBN 128
#define TBK 64

template <int OUT_BF16>
__global__ __launch_bounds__(256, 2) void gemm128_kernel(const unsigned short* __restrict__ A,
                                                         const unsigned short* __restrict__ Bt,
                                                         void* __restrict__ Cv,
                                                         int M, int N, int K) {
  __shared__ __attribute__((aligned(16))) unsigned short As[2][TBM * TBK];
  __shared__ __attribute__((aligned(16))) unsigned short Bs[2][TBN * TBK];
  const int tid = threadIdx.x;
  const int wave = tid >> 6, lane = tid & 63;
  const int lg = lane >> 4, ll = lane & 15;
  const int wm = wave >> 1, wn = wave & 1;     // 2x2 wave grid, 64x64 each

  // XCD-chunked block swizzle (bijective when nwg%8==0)
  int gx = gridDim.x, nwg = gx * gridDim.y;
  int flat = blockIdx.y * gx + blockIdx.x;
  int bx = blockIdx.x, by = blockIdx.y;
  if ((nwg & 7) == 0) {
    int t = (flat & 7) * (nwg >> 3) + (flat >> 3);
    bx = t % gx; by = t / gx;
  }
  const int m0 = by * TBM, n0 = bx * TBN;

  f32x4 acc[4][4] = {};
  const int NT = K >> 6;   // K/64, >= 2 here

  // tile = 128 rows x 8 chunks(16B); physical chunk p = c ^ (row&7).
  auto stage = [&](int t, int buf) {
    const int k0 = t * TBK;
    #pragma unroll
    for (int i = 0; i < 4; ++i) {
      int ci  = (i * 4 + wave) * 64 + lane;
      int row = ci >> 3;
      int cg  = (ci & 7) ^ (row & 7);
      GLL16(A + (size_t)(m0 + row) * K + k0 + cg * 8, &As[buf][(i * 4 + wave) * 512]);
    }
    #pragma unroll
    for (int i = 0; i < 4; ++i) {
      int ci  = (i * 4 + wave) * 64 + lane;
      int row = ci >> 3;
      int cg  = (ci & 7) ^ (row & 7);
      GLL16(Bt + (size_t)(n0 + row) * K + k0 + cg * 8, &Bs[buf][(i * 4 + wave) * 512]);
    }
  };

  stage(0, 0);
  stage(1, 1);

  for (int t = 0; t < NT; ++t) {
    const int cur = t & 1;
    if (t + 1 < NT) asm volatile("s_waitcnt vmcnt(8)" ::: "memory");
    else            asm volatile("s_waitcnt vmcnt(0)" ::: "memory");
    __builtin_amdgcn_s_barrier();      // buf cur visible to all waves

    const unsigned short* Ac = &As[cur][0];
    const unsigned short* Bc = &Bs[cur][0];
    bf16x8 afr[2][4], bfr[2][4];
    #pragma unroll
    for (int kk = 0; kk < 2; ++kk)
      #pragma unroll
      for (int i = 0; i < 4; ++i) {
        int ra = wm * 64 + i * 16 + ll;
        afr[kk][i] = *reinterpret_cast<const bf16x8*>(
            &Ac[ra * 64 + (((kk * 4 + lg) ^ (ra & 7)) * 8)]);
        int rb = wn * 64 + i * 16 + ll;
        bfr[kk][i] = *reinterpret_cast<const bf16x8*>(
            &Bc[rb * 64 + (((kk * 4 + lg) ^ (rb & 7)) * 8)]);
      }
    // MFMAs: compiler inserts fine-grained lgkmcnt per dependency
    __builtin_amdgcn_s_setprio(1);
    #pragma unroll
    for (int kk = 0; kk < 2; ++kk)
      #pragma unroll
      for (int i = 0; i < 4; ++i)
        #pragma unroll
        for (int j = 0; j < 4; ++j)
          acc[i][j] = __builtin_amdgcn_mfma_f32_16x16x32_bf16(afr[kk][i], bfr[kk][j],
                                                              acc[i][j], 0, 0, 0);
    __builtin_amdgcn_s_setprio(0);

    __builtin_amdgcn_s_barrier();      // all waves consumed buf cur
    if (t + 2 < NT) stage(t + 2, cur); // refill vacated buffer (off critical path)
  }

  #pragma unroll
  for (int i = 0; i < 4; ++i)
    #pragma unroll
    for (int j = 0; j < 4; ++j) {
      int col  = n0 + wn * 64 + j * 16 + ll;
      int rowb = m0 + wm * 64 + i * 16 + lg * 4;
      #pragma unroll
      for (int r = 0; r < 4; ++r) {
        size_t idx = (size_t)(rowb + r) * N + col;
        if (OUT_BF16) ((unsigned short*)Cv)[idx] = f2bf(acc[i][j][r]);
        else          ((float*)Cv)[idx]          = acc[i][j][r];
      }
    }
}

// ---------------------------------------------------------------- bias + RoPE + relayout (merged)
// qkv: [L][4608] bf16. cols 0..4095 = Q, 4096..4351 = K, 4352..4607 = V.
__global__ __launch_bounds__(128) void qkv_post_kernel(const unsigned short* __restrict__ qkv,
                                                       const float* __restrict__ bq,
                                                       const float* __restrict__ bk,
                                                       const float* __restrict__ bv,
                                                       const float* __restrict__ cosT,
                                                       const float* __restrict__ sinT,
                                                       unsigned short* __restrict__ qb,
                                                       unsigned short* __restrict__ kb,
                                                       unsigned short* __restrict__ vt) {
  int l = blockIdx.x, y = blockIdx.y, d = threadIdx.x;
  if (y < 34) {                                 // Q or K: bias + RoPE
    const bool isq = (y < 32);
    const int hh = isq ? y : (y - 32);
    const float* bias = isq ? bq : bk;
    size_t base = (size_t)l * NQKV + (isq ? 0 : 4096) + hh * DH;
    float v = bf2f(qkv[base + d]) + bias[hh * DH + d];
    float o;
    if (d < 32) {
      float x2 = bf2f(qkv[base + d + 32]) + bias[hh * DH + d + 32];
      o = v * cosT[l * 32 + d] - x2 * sinT[l * 32 + d];
    } else if (d < 64) {
      int i = d - 32;
      float x1 = bf2f(qkv[base + i]) + bias[hh * DH + i];
      o = v * cosT[l * 32 + i] + x1 * sinT[l * 32 + i];
    } else {
      o = v;
    }
    if (isq) qb[((size_t)hh * L_SEQ + l) * DH + d] = f2bf(o * QSCALE);
    else     kb[((size_t)hh * L_SEQ + l) * DH + d] = f2bf(o);
  } else {                                      // V: bias, stored transposed vt[g][d][l]
    int g = y - 34;
    float o = bf2f(qkv[(size_t)l * NQKV + 4352 + g * DH + d]) + bv[g * DH + d];
    vt[((size_t)g * DH + d) * L_SEQ + l] = f2bf(o);
  }
}

// ---------------------------------------------------------------- flash attention
// grid (16, H); 256 threads = 4 waves. Causal fold-pairing: block pair p handles
// q-tiles p and 31-p (QB=64) sequentially -> uniform 33 KV-tiles per block.
// SWAPPED QK^T: s = mfma(K,Q) -> lane owns q-row q=ll; s[cf][r] = S[k=cf*16+lg*4+r][q=ll].
// In-lane softmax; P stored [16 q][64 k] bf16, chunk-swizzled (^ll&7); PV reads b128.
__global__ __launch_bounds__(256) void attn_kernel(const unsigned short* __restrict__ qg,
                                                   const unsigned short* __restrict__ kb,
                                                   const unsigned short* __restrict__ vt,
                                                   unsigned short* __restrict__ ob) {
  __shared__ __attribute__((aligned(16))) unsigned short Ks[2][64 * 128];
  __shared__ __attribute__((aligned(16))) unsigned short Vs[2][128 * 64];
  __shared__ __attribute__((aligned(16))) unsigned short Ps[4][16 * 64];

  const int pair = blockIdx.x, h = blockIdx.y;
  const int g = h >> 4;                         // 16 q-heads per kv-head
  const int tid = threadIdx.x, wave = tid >> 6, lane = tid & 63;
  const int lg = lane >> 4, ll = lane & 15;

  const int krow = (lane >> 4);
  const int kcg0 = (lane & 15);
  const int vrow = (lane >> 3);
  const int vcg0 = (lane & 7);

  #pragma unroll
  for (int seg = 0; seg < 2; ++seg) {
    const int qt = seg ? (31 - pair) : pair;
    const int q0 = qt * 64 + wave * 16;

    bf16x8 qf[4];
    #pragma unroll
    for (int f = 0; f < 4; ++f)
      qf[f] = *reinterpret_cast<const bf16x8*>(
          qg + ((size_t)h * L_SEQ + q0 + ll) * DH + f * 32 + lg * 8);

    f32x4 of[8] = {};
    float m = -1e30f, lsum = 0.f;               // per-lane: q-row = ll

    const int kvN = qt + 1;
    int cur = 0;

    #pragma unroll
    for (int c = 0; c < 4; ++c) {
      int issue = wave * 4 + c;
      int rk = issue * 4 + krow;
      GLL16(kb + ((size_t)g * L_SEQ + rk) * DH + (kcg0 ^ (rk & 7)) * 8, &Ks[0][issue * 512]);
      int rv = issue * 8 + vrow;
      GLL16(vt + ((size_t)g * DH + rv) * L_SEQ + (vcg0 ^ (rv & 7)) * 8, &Vs[0][issue * 512]);
    }
    __syncthreads();

    for (int t = 0; t < kvN; ++t) {
      if (t + 1 < kvN) {
        int kv1 = (t + 1) * 64;
        #pragma unroll
        for (int c = 0; c < 4; ++c) {
          int issue = wave * 4 + c;
          int rk = issue * 4 + krow;
          GLL16(kb + ((size_t)g * L_SEQ + kv1 + rk) * DH + (kcg0 ^ (rk & 7)) * 8,
                &Ks[cur ^ 1][issue * 512]);
          int rv = issue * 8 + vrow;
          GLL16(vt + ((size_t)g * DH + rv) * L_SEQ + kv1 + (vcg0 ^ (rv & 7)) * 8,
                &Vs[cur ^ 1][issue * 512]);
        }
      }

      // ---- QK^T (swapped): s[cf] = K-rows x Q-rows
      f32x4 s[4] = {};
      const unsigned short* Kc = &Ks[cur][0];
      #pragma unroll
      for (int cf = 0; cf < 4; ++cf) {
        bf16x8 kf[4];
        #pragma unroll
        for (int f = 0; f < 4; ++f) {
          int rk = cf * 16 + ll;
          int cc = (f * 4 + lg) ^ (rk & 7);
          kf[f] = *reinterpret_cast<const bf16x8*>(&Kc[rk * 128 + cc * 8]);
        }
        __builtin_amdgcn_s_setprio(1);
        #pragma unroll
        for (int f = 0; f < 4; ++f)
          s[cf] = __builtin_amdgcn_mfma_f32_16x16x32_bf16(kf[f], qf[f], s[cf], 0, 0, 0);
        __builtin_amdgcn_s_setprio(0);
      }

      // ---- causal mask (diagonal tile): k_local > q_local
      if (t == qt) {
        #pragma unroll
        for (int cf = 0; cf < 4; ++cf)
          #pragma unroll
          for (int r = 0; r < 4; ++r)
            if (cf * 16 + lg * 4 + r > wave * 16 + ll) s[cf][r] = -1e30f;
      }

      // ---- defer-max online softmax (in-lane)
      float pmax = -1e30f;
      #pragma unroll
      for (int cf = 0; cf < 4; ++cf)
        #pragma unroll
        for (int r = 0; r < 4; ++r) pmax = fmaxf(pmax, s[cf][r]);
      if (!__all(pmax - m <= 8.f)) {
        float mx = fmaxf(pmax, __shfl_xor(pmax, 16));
        mx = fmaxf(mx, __shfl_xor(mx, 32));
        float mnew = fmaxf(m, mx);
        float alpha = __expf(m - mnew);
        m = mnew;
        lsum *= alpha;
        float af[4];
        #pragma unroll
        for (int r = 0; r < 4; ++r) af[r] = __shfl(alpha, lg * 4 + r);
        #pragma unroll
        for (int ds = 0; ds < 8; ++ds)
          #pragma unroll
          for (int r = 0; r < 4; ++r) of[ds][r] *= af[r];
      }

      // ---- exp + pack + P write (4x ds_write_b64, swizzled [16][64])
      unsigned short* pw = &Ps[wave][0];
      float psum = 0.f;
      #pragma unroll
      for (int cf = 0; cf < 4; ++cf) {
        float p0 = __expf(s[cf][0] - m), p1 = __expf(s[cf][1] - m);
        float p2 = __expf(s[cf][2] - m), p3 = __expf(s[cf][3] - m);
        psum += (p0 + p1) + (p2 + p3);
        uint2 w;
        w.x = (unsigned)f2bf(p0) | ((unsigned)f2bf(p1) << 16);
        w.y = (unsigned)f2bf(p2) | ((unsigned)f2bf(p3) << 16);
        int chunk = (cf * 2 + (lg >> 1)) ^ (ll & 7);
        *reinterpret_cast<uint2*>(&pw[ll * 64 + chunk * 8 + (lg & 1) * 4]) = w;
      }
      lsum += psum;

      bf16x8 pa[2];
      #pragma unroll
      for (int ks = 0; ks < 2; ++ks)
        pa[ks] = *reinterpret_cast<const bf16x8*>(
            &pw[ll * 64 + (((ks * 4 + lg) ^ (ll & 7)) * 8)]);

      // ---- PV
      const unsigned short* Vc = &Vs[cur][0];
      #pragma unroll
      for (int ds = 0; ds < 8; ++ds) {
        bf16x8 vf[2];
        #pragma unroll
        for (int ks = 0; ks < 2; ++ks) {
          int dl = ds * 16 + ll;
          int cc = (ks * 4 + lg) ^ (dl & 7);
          vf[ks] = *reinterpret_cast<const bf16x8*>(&Vc[dl * 64 + cc * 8]);
        }
        __builtin_amdgcn_s_setprio(1);
        #pragma unroll
        for (int ks = 0; ks < 2; ++ks)
          of[ds] = __builtin_amdgcn_mfma_f32_16x16x32_bf16(pa[ks], vf[ks], of[ds], 0, 0, 0);
        __builtin_amdgcn_s_setprio(0);
      }

      __syncthreads();
      cur ^= 1;
    }

    // ---- epilogue: total l across the 4 dup lanes, broadcast inverse to of rows
    float tot = lsum + __shfl_xor(lsum, 16);
    tot += __shfl_xor(tot, 32);
    float inv = 1.f / tot;
    float invr[4];
    #pragma unroll
    for (int r = 0; r < 4; ++r) invr[r] = __shfl(inv, lg * 4 + r);
    #pragma unroll
    for (int ds = 0; ds < 8; ++ds)
      #pragma unroll
      for (int r = 0; r < 4; ++r) {
        int row = q0 + lg * 4 + r;
        ob[(size_t)row * (NH * DH) + h * DH + ds * 16 + ll] = f2bf(of[ds][r] * invr[r]);
      }
    __syncthreads();
  }
}

// ---------------------------------------------------------------- launch
extern "C" void kernel_launch(void* const* d_in, const int* in_sizes, int n_in,
                              void* d_out, int out_size, void* d_ws, size_t ws_size,
                              hipStream_t stream) {
  (void)in_sizes; (void)n_in; (void)out_size; (void)ws_size;
  const float* x    = (const float*)d_in[0];
  const float* Wq   = (const float*)d_in[1];
  const float* bq   = (const float*)d_in[2];
  const float* Wk   = (const float*)d_in[3];
  const float* bk   = (const float*)d_in[4];
  const float* Wv   = (const float*)d_in[5];
  const float* bv   = (const float*)d_in[6];
  const float* Wo   = (const float*)d_in[7];
  const float* cosT = (const float*)d_in[8];
  const float* sinT = (const float*)d_in[9];
  // d_in[10] = attention_mask: unused (causal mask computed arithmetically)

  char* ws = (char*)d_ws;
  size_t off = 0;
  auto alloc = [&](size_t bytes) { void* p = ws + off; off += (bytes + 255) & ~(size_t)255; return p; };
  unsigned short* xb     = (unsigned short*)alloc((size_t)L_SEQ * HID * 2);
  unsigned short* Wqkvt  = (unsigned short*)alloc((size_t)NQKV * HID * 2);
  unsigned short* Wot    = (unsigned short*)alloc((size_t)HID * HID * 2);
  unsigned short* qkvlin = (unsigned short*)alloc((size_t)L_SEQ * NQKV * 2);
  unsigned short* qbuf   = (unsigned short*)alloc((size_t)NH * L_SEQ * DH * 2);
  unsigned short* kbuf   = (unsigned short*)alloc((size_t)NKV * L_SEQ * DH * 2);
  unsigned short* vtb    = (unsigned short*)alloc((size_t)NKV * DH * L_SEQ * 2);
  unsigned short* attno  = (unsigned short*)alloc((size_t)L_SEQ * HID * 2);

  cast_bf16_kernel<<<(L_SEQ * HID / 4 + 255) / 256, 256, 0, stream>>>(x, xb, L_SEQ * HID / 4);
  transpose_cast_kernel<<<dim3(HID / 64, HID / 64), 256, 0, stream>>>(Wq, Wqkvt, HID, HID);
  transpose_cast_kernel<<<dim3(256 / 64, HID / 64), 256, 0, stream>>>(Wk, Wqkvt + (size_t)4096 * HID, HID, 256);
  transpose_cast_kernel<<<dim3(256 / 64, HID / 64), 256, 0, stream>>>(Wv, Wqkvt + (size_t)4352 * HID, HID, 256);
  transpose_cast_kernel<<<dim3(HID / 64, HID / 64), 256, 0, stream>>>(Wo, Wot, HID, HID);

  gemm128_kernel<1><<<dim3(NQKV / TBN, L_SEQ / TBM), 256, 0, stream>>>(xb, Wqkvt, qkvlin, L_SEQ, NQKV, HID);

  qkv_post_kernel<<<dim3(L_SEQ, 36), 128, 0, stream>>>(qkvlin, bq, bk, bv, cosT, sinT,
                                                       qbuf, kbuf, vtb);

  attn_kernel<<<dim3(16, NH), 256, 0, stream>>>(qbuf, kbuf, vtb, attno);

  gemm128_kernel<0><<<dim3(HID / TBN, L_SEQ / TBM), 256, 0, stream>>>(attno, Wot, (float*)d_out, L_SEQ, HID, HID);
}

// Round 8
// 310.556 us; speedup vs baseline: 1.4078x; 1.1358x over previous
//
// GLM4 attention block (B=1, L=2048, HID=4096, H=32, KV=2, D=128, ROT=64) on MI355X.
// Round 8: GEMM loop reverted to round-6 ordering (vmcnt->bar->reads->lgkm0->bar->
//   stage->MFMA, 111us config). Bias+RoPE fused into QKV-GEMM epilogue (tile==head);
//   V via vlin + tiny vtrans. Attn (swapped QK^T) and transposes from round 7.
#include <hip/hip_runtime.h>
#include <stdint.h>

#define L_SEQ 2048
#define HID   4096
#define NH    32
#define NKV   2
#define DH    128
#define NQKV  4608                     // H*D + 2*KV*D
#define QSCALE 0.088388347648318447f   // 128^-0.5

typedef __bf16 bf16x8 __attribute__((ext_vector_type(8)));
typedef float  f32x4  __attribute__((ext_vector_type(4)));

__device__ __forceinline__ unsigned short f2bf(float f) {
  union { float f; unsigned u; } cv; cv.f = f;
  unsigned u = cv.u;
  return (unsigned short)((u + 0x7fffu + ((u >> 16) & 1u)) >> 16);   // RNE, finite-only
}
__device__ __forceinline__ float bf2f(unsigned short h) {
  union { unsigned u; float f; } cv; cv.u = (unsigned)h << 16; return cv.f;
}

// async global->LDS, 16B per lane; LDS dest = wave-uniform base + lane*16
#define GLL16(gsrc, ldst)                                                              \
  __builtin_amdgcn_global_load_lds(                                                    \
      (const __attribute__((address_space(1))) unsigned int*)(gsrc),                   \
      (__attribute__((address_space(3))) unsigned int*)(ldst), 16, 0, 0)

// ---------------------------------------------------------------- casts
__global__ __launch_bounds__(256) void cast_bf16_kernel(const float* __restrict__ in,
                                                        unsigned short* __restrict__ out,
                                                        int n4) {
  int i = blockIdx.x * 256 + threadIdx.x;
  if (i >= n4) return;
  float4 v = reinterpret_cast<const float4*>(in)[i];
  ushort4 o;
  o.x = f2bf(v.x); o.y = f2bf(v.y); o.z = f2bf(v.z); o.w = f2bf(v.w);
  reinterpret_cast<ushort4*>(out)[i] = o;
}

// in: (R,C) fp32 row-major -> out: (C,R) bf16 row-major. 64x64 tiles, 256 threads.
__global__ __launch_bounds__(256) void transpose_cast_kernel(const float* __restrict__ in,
                                                             unsigned short* __restrict__ out,
                                                             int R, int C) {
  __shared__ float tile[64][65];
  const int c0 = blockIdx.x * 64, r0 = blockIdx.y * 64;
  const int tid = threadIdx.x;
  #pragma unroll
  for (int it = 0; it < 4; ++it) {
    int row = it * 16 + (tid >> 4);
    float4 v = *reinterpret_cast<const float4*>(&in[(size_t)(r0 + row) * C + c0 + (tid & 15) * 4]);
    tile[row][(tid & 15) * 4 + 0] = v.x;
    tile[row][(tid & 15) * 4 + 1] = v.y;
    tile[row][(tid & 15) * 4 + 2] = v.z;
    tile[row][(tid & 15) * 4 + 3] = v.w;
  }
  __syncthreads();
  #pragma unroll
  for (int it = 0; it < 8; ++it) {
    int c  = it * 8 + (tid >> 5);
    int rp = tid & 31;
    unsigned u = (unsigned)f2bf(tile[2 * rp][c]) | ((unsigned)f2bf(tile[2 * rp + 1][c]) << 16);
    *reinterpret_cast<unsigned*>(&out[(size_t)(c0 + c) * R + r0 + 2 * rp]) = u;
  }
}

// vlin[g][l][128] bf16 -> vt[g][d][l] bf16 (64x64 tiles)
__global__ __launch_bounds__(256) void vtrans_kernel(const unsigned short* __restrict__ in,
                                                     unsigned short* __restrict__ out) {
  __shared__ unsigned short tile[64][72];
  const int l0 = blockIdx.x * 64, d0 = blockIdx.y * 64, g = blockIdx.z;
  const int tid = threadIdx.x;
  #pragma unroll
  for (int it = 0; it < 2; ++it) {
    int l = it * 32 + (tid >> 3);
    *reinterpret_cast<uint4*>(&tile[l][(tid & 7) * 8]) =
        *reinterpret_cast<const uint4*>(&in[((size_t)g * L_SEQ + l0 + l) * DH + d0 + (tid & 7) * 8]);
  }
  __syncthreads();
  #pragma unroll
  for (int it = 0; it < 2; ++it) {
    int d = it * 32 + (tid >> 3);
    unsigned short tmp[8];
    #pragma unroll
    for (int e = 0; e < 8; ++e) tmp[e] = tile[(tid & 7) * 8 + e][d];
    *reinterpret_cast<uint4*>(&out[((size_t)g * DH + d0 + d) * L_SEQ + l0 + (tid & 7) * 8]) =
        *reinterpret_cast<uint4*>(tmp);
  }
}

// ---------------------------------------------------------------- GEMM  C(M,N) = A(M,K) * Bt(N,K)^T
// BM=BN=128, BK=64; 4 waves, wave-tile 64x64 (4x4 16x16 frags);
// 2-buffer LDS (64KB -> 2 blocks/CU), counted vmcnt(8); round-6 ordering:
//   vmcnt -> bar -> 16 frag reads -> lgkm(0) -> bar -> stage(t+2) -> MFMA.
// MODE 0: plain fp32 C write. MODE 1: fused QKV epilogue (bias+RoPE, tile==head).
#define TBM 128
#define TBN 128
#define TBK 64

template <int MODE>
__global__ __launch_bounds__(256, 2) void gemm128_kernel(const unsigned short* __restrict__ A,
                                                         const unsigned short* __restrict__ Bt,
                                                         float* __restrict__ C,
                                                         const float* __restrict__ bq,
                                                         const float* __restrict__ bk,
                                                         const float* __restrict__ bv,
                                                         const float* __restrict__ cosT,
                                                         const float* __restrict__ sinT,
                                                         unsigned short* __restrict__ qb,
                                                         unsigned short* __restrict__ kb,
                                                         unsigned short* __restrict__ vlin,
                                                         int M, int N, int K) {
  __shared__ __attribute__((aligned(16))) unsigned short As[2][TBM * TBK];
  __shared__ __attribute__((aligned(16))) unsigned short Bs[2][TBN * TBK];
  const int tid = threadIdx.x;
  const int wave = tid >> 6, lane = tid & 63;
  const int lg = lane >> 4, ll = lane & 15;
  const int wm = wave >> 1, wn = wave & 1;     // 2x2 wave grid, 64x64 each

  // XCD-chunked block swizzle (bijective when nwg%8==0)
  int gx = gridDim.x, nwg = gx * gridDim.y;
  int flat = blockIdx.y * gx + blockIdx.x;
  int bx = blockIdx.x, by = blockIdx.y;
  if ((nwg & 7) == 0) {
    int t = (flat & 7) * (nwg >> 3) + (flat >> 3);
    bx = t % gx; by = t / gx;
  }
  const int m0 = by * TBM, n0 = bx * TBN;

  f32x4 acc[4][4] = {};
  const int NT = K >> 6;   // K/64, >= 2 here

  // tile = 128 rows x 8 chunks(16B); physical chunk p = c ^ (row&7).
  auto stage = [&](int t, int buf) {
    const int k0 = t * TBK;
    #pragma unroll
    for (int i = 0; i < 4; ++i) {
      int ci  = (i * 4 + wave) * 64 + lane;
      int row = ci >> 3;
      int cg  = (ci & 7) ^ (row & 7);
      GLL16(A + (size_t)(m0 + row) * K + k0 + cg * 8, &As[buf][(i * 4 + wave) * 512]);
    }
    #pragma unroll
    for (int i = 0; i < 4; ++i) {
      int ci  = (i * 4 + wave) * 64 + lane;
      int row = ci >> 3;
      int cg  = (ci & 7) ^ (row & 7);
      GLL16(Bt + (size_t)(n0 + row) * K + k0 + cg * 8, &Bs[buf][(i * 4 + wave) * 512]);
    }
  };

  stage(0, 0);
  stage(1, 1);

  for (int t = 0; t < NT; ++t) {
    const int cur = t & 1;
    if (t + 1 < NT) asm volatile("s_waitcnt vmcnt(8)" ::: "memory");
    else            asm volatile("s_waitcnt vmcnt(0)" ::: "memory");
    __builtin_amdgcn_s_barrier();      // buf cur visible to all waves

    const unsigned short* Ac = &As[cur][0];
    const unsigned short* Bc = &Bs[cur][0];
    bf16x8 afr[2][4], bfr[2][4];
    #pragma unroll
    for (int kk = 0; kk < 2; ++kk)
      #pragma unroll
      for (int i = 0; i < 4; ++i) {
        int ra = wm * 64 + i * 16 + ll;
        afr[kk][i] = *reinterpret_cast<const bf16x8*>(
            &Ac[ra * 64 + (((kk * 4 + lg) ^ (ra & 7)) * 8)]);
        int rb = wn * 64 + i * 16 + ll;
        bfr[kk][i] = *reinterpret_cast<const bf16x8*>(
            &Bc[rb * 64 + (((kk * 4 + lg) ^ (rb & 7)) * 8)]);
      }
    asm volatile("s_waitcnt lgkmcnt(0)" ::: "memory");
    __builtin_amdgcn_s_barrier();      // all waves done reading buf cur
    if (t + 2 < NT) stage(t + 2, cur); // refill vacated buffer (overlaps MFMA)

    __builtin_amdgcn_s_setprio(1);
    #pragma unroll
    for (int kk = 0; kk < 2; ++kk)
      #pragma unroll
      for (int i = 0; i < 4; ++i)
        #pragma unroll
        for (int j = 0; j < 4; ++j)
          acc[i][j] = __builtin_amdgcn_mfma_f32_16x16x32_bf16(afr[kk][i], bfr[kk][j],
                                                              acc[i][j], 0, 0, 0);
    __builtin_amdgcn_s_setprio(0);
  }

  if (MODE == 0) {
    #pragma unroll
    for (int i = 0; i < 4; ++i)
      #pragma unroll
      for (int j = 0; j < 4; ++j) {
        int col  = n0 + wn * 64 + j * 16 + ll;
        int rowb = m0 + wm * 64 + i * 16 + lg * 4;
        #pragma unroll
        for (int r = 0; r < 4; ++r)
          C[(size_t)(rowb + r) * N + col] = acc[i][j][r];
      }
  } else {
    // Fused QKV epilogue: tile n0 covers exactly one 128-wide head slice.
    // region: n0<4096 -> Q head h ; 4096..4351 -> K g ; 4352.. -> V g.
    const int region = (n0 < 4096) ? 0 : ((n0 < 4352) ? 1 : 2);
    const int hh = (region == 0) ? (n0 >> 7) : ((region == 1) ? ((n0 - 4096) >> 7) : ((n0 - 4352) >> 7));
    const float* bias = (region == 0) ? bq : ((region == 1) ? bk : bv);
    // bias add (d = wn*64 + j*16 + ll within head)
    #pragma unroll
    for (int j = 0; j < 4; ++j) {
      float bj = bias[hh * DH + wn * 64 + j * 16 + ll];
      #pragma unroll
      for (int i = 0; i < 4; ++i)
        #pragma unroll
        for (int r = 0; r < 4; ++r) acc[i][j][r] += bj;
    }
    // RoPE for Q/K on wn==0 half (d in [0,64): pairs (j, j^2), freq idx (j&1)*16+ll)
    if (region < 2 && wn == 0) {
      #pragma unroll
      for (int i = 0; i < 4; ++i)
        #pragma unroll
        for (int r = 0; r < 4; ++r) {
          int l = m0 + wm * 64 + i * 16 + lg * 4 + r;
          float c0 = cosT[l * 32 + ll],      s0 = sinT[l * 32 + ll];
          float c1 = cosT[l * 32 + 16 + ll], s1 = sinT[l * 32 + 16 + ll];
          float x10 = acc[i][0][r], x20 = acc[i][2][r];
          float x11 = acc[i][1][r], x21 = acc[i][3][r];
          acc[i][0][r] = x10 * c0 - x20 * s0;
          acc[i][2][r] = x20 * c0 + x10 * s0;
          acc[i][1][r] = x11 * c1 - x21 * s1;
          acc[i][3][r] = x21 * c1 + x11 * s1;
        }
    }
    const float scale = (region == 0) ? QSCALE : 1.f;
    unsigned short* dst = (region == 0) ? qb : ((region == 1) ? kb : vlin);
    #pragma unroll
    for (int i = 0; i < 4; ++i)
      #pragma unroll
      for (int j = 0; j < 4; ++j) {
        int d = wn * 64 + j * 16 + ll;
        #pragma unroll
        for (int r = 0; r < 4; ++r) {
          int l = m0 + wm * 64 + i * 16 + lg * 4 + r;
          dst[((size_t)hh * L_SEQ + l) * DH + d] = f2bf(acc[i][j][r] * scale);
        }
      }
  }
}

// ---------------------------------------------------------------- flash attention
// grid (16, H); 256 threads = 4 waves. Causal fold-pairing: block pair p handles
// q-tiles p and 31-p (QB=64) sequentially -> uniform 33 KV-tiles per block.
// SWAPPED QK^T: s = mfma(K,Q) -> lane owns q-row q=ll; in-lane softmax;
// P stored [16 q][64 k] bf16, chunk-swizzled (^ll&7); PV reads b128.
__global__ __launch_bounds__(256) void attn_kernel(const unsigned short* __restrict__ qg,
                                                   const unsigned short* __restrict__ kb,
                                                   const unsigned short* __restrict__ vt,
                                                   unsigned short* __restrict__ ob) {
  __shared__ __attribute__((aligned(16))) unsigned short Ks[2][64 * 128];
  __shared__ __attribute__((aligned(16))) unsigned short Vs[2][128 * 64];
  __shared__ __attribute__((aligned(16))) unsigned short Ps[4][16 * 64];

  const int pair = blockIdx.x, h = blockIdx.y;
  const int g = h >> 4;                         // 16 q-heads per kv-head
  const int tid = threadIdx.x, wave = tid >> 6, lane = tid & 63;
  const int lg = lane >> 4, ll = lane & 15;

  const int krow = (lane >> 4);
  const int kcg0 = (lane & 15);
  const int vrow = (lane >> 3);
  const int vcg0 = (lane & 7);

  #pragma unroll
  for (int seg = 0; seg < 2; ++seg) {
    const int qt = seg ? (31 - pair) : pair;
    const int q0 = qt * 64 + wave * 16;

    bf16x8 qf[4];
    #pragma unroll
    for (int f = 0; f < 4; ++f)
      qf[f] = *reinterpret_cast<const bf16x8*>(
          qg + ((size_t)h * L_SEQ + q0 + ll) * DH + f * 32 + lg * 8);

    f32x4 of[8] = {};
    float m = -1e30f, lsum = 0.f;               // per-lane: q-row = ll

    const int kvN = qt + 1;
    int cur = 0;

    #pragma unroll
    for (int c = 0; c < 4; ++c) {
      int issue = wave * 4 + c;
      int rk = issue * 4 + krow;
      GLL16(kb + ((size_t)g * L_SEQ + rk) * DH + (kcg0 ^ (rk & 7)) * 8, &Ks[0][issue * 512]);
      int rv = issue * 8 + vrow;
      GLL16(vt + ((size_t)g * DH + rv) * L_SEQ + (vcg0 ^ (rv & 7)) * 8, &Vs[0][issue * 512]);
    }
    __syncthreads();

    for (int t = 0; t < kvN; ++t) {
      if (t + 1 < kvN) {
        int kv1 = (t + 1) * 64;
        #pragma unroll
        for (int c = 0; c < 4; ++c) {
          int issue = wave * 4 + c;
          int rk = issue * 4 + krow;
          GLL16(kb + ((size_t)g * L_SEQ + kv1 + rk) * DH + (kcg0 ^ (rk & 7)) * 8,
                &Ks[cur ^ 1][issue * 512]);
          int rv = issue * 8 + vrow;
          GLL16(vt + ((size_t)g * DH + rv) * L_SEQ + kv1 + (vcg0 ^ (rv & 7)) * 8,
                &Vs[cur ^ 1][issue * 512]);
        }
      }

      // ---- QK^T (swapped): s[cf] = K-rows x Q-rows
      f32x4 s[4] = {};
      const unsigned short* Kc = &Ks[cur][0];
      #pragma unroll
      for (int cf = 0; cf < 4; ++cf) {
        bf16x8 kf[4];
        #pragma unroll
        for (int f = 0; f < 4; ++f) {
          int rk = cf * 16 + ll;
          int cc = (f * 4 + lg) ^ (rk & 7);
          kf[f] = *reinterpret_cast<const bf16x8*>(&Kc[rk * 128 + cc * 8]);
        }
        __builtin_amdgcn_s_setprio(1);
        #pragma unroll
        for (int f = 0; f < 4; ++f)
          s[cf] = __builtin_amdgcn_mfma_f32_16x16x32_bf16(kf[f], qf[f], s[cf], 0, 0, 0);
        __builtin_amdgcn_s_setprio(0);
      }

      // ---- causal mask (diagonal tile): k_local > q_local
      if (t == qt) {
        #pragma unroll
        for (int cf = 0; cf < 4; ++cf)
          #pragma unroll
          for (int r = 0; r < 4; ++r)
            if (cf * 16 + lg * 4 + r > wave * 16 + ll) s[cf][r] = -1e30f;
      }

      // ---- defer-max online softmax (in-lane)
      float pmax = -1e30f;
      #pragma unroll
      for (int cf = 0; cf < 4; ++cf)
        #pragma unroll
        for (int r = 0; r < 4; ++r) pmax = fmaxf(pmax, s[cf][r]);
      if (!__all(pmax - m <= 8.f)) {
        float mx = fmaxf(pmax, __shfl_xor(pmax, 16));
        mx = fmaxf(mx, __shfl_xor(mx, 32));
        float mnew = fmaxf(m, mx);
        float alpha = __expf(m - mnew);
        m = mnew;
        lsum *= alpha;
        float af[4];
        #pragma unroll
        for (int r = 0; r < 4; ++r) af[r] = __shfl(alpha, lg * 4 + r);
        #pragma unroll
        for (int ds = 0; ds < 8; ++ds)
          #pragma unroll
          for (int r = 0; r < 4; ++r) of[ds][r] *= af[r];
      }

      // ---- exp + pack + P write (4x ds_write_b64, swizzled [16][64])
      unsigned short* pw = &Ps[wave][0];
      float psum = 0.f;
      #pragma unroll
      for (int cf = 0; cf < 4; ++cf) {
        float p0 = __expf(s[cf][0] - m), p1 = __expf(s[cf][1] - m);
        float p2 = __expf(s[cf][2] - m), p3 = __expf(s[cf][3] - m);
        psum += (p0 + p1) + (p2 + p3);
        uint2 w;
        w.x = (unsigned)f2bf(p0) | ((unsigned)f2bf(p1) << 16);
        w.y = (unsigned)f2bf(p2) | ((unsigned)f2bf(p3) << 16);
        int chunk = (cf * 2 + (lg >> 1)) ^ (ll & 7);
        *reinterpret_cast<uint2*>(&pw[ll * 64 + chunk * 8 + (lg & 1) * 4]) = w;
      }
      lsum += psum;

      bf16x8 pa[2];
      #pragma unroll
      for (int ks = 0; ks < 2; ++ks)
        pa[ks] = *reinterpret_cast<const bf16x8*>(
            &pw[ll * 64 + (((ks * 4 + lg) ^ (ll & 7)) * 8)]);

      // ---- PV
      const unsigned short* Vc = &Vs[cur][0];
      #pragma unroll
      for (int ds = 0; ds < 8; ++ds) {
        bf16x8 vf[2];
        #pragma unroll
        for (int ks = 0; ks < 2; ++ks) {
          int dl = ds * 16 + ll;
          int cc = (ks * 4 + lg) ^ (dl & 7);
          vf[ks] = *reinterpret_cast<const bf16x8*>(&Vc[dl * 64 + cc * 8]);
        }
        __builtin_amdgcn_s_setprio(1);
        #pragma unroll
        for (int ks = 0; ks < 2; ++ks)
          of[ds] = __builtin_amdgcn_mfma_f32_16x16x32_bf16(pa[ks], vf[ks], of[ds], 0, 0, 0);
        __builtin_amdgcn_s_setprio(0);
      }

      __syncthreads();
      cur ^= 1;
    }

    // ---- epilogue: total l across the 4 dup lanes, broadcast inverse to of rows
    float tot = lsum + __shfl_xor(lsum, 16);
    tot += __shfl_xor(tot, 32);
    float inv = 1.f / tot;
    float invr[4];
    #pragma unroll
    for (int r = 0; r < 4; ++r) invr[r] = __shfl(inv, lg * 4 + r);
    #pragma unroll
    for (int ds = 0; ds < 8; ++ds)
      #pragma unroll
      for (int r = 0; r < 4; ++r) {
        int row = q0 + lg * 4 + r;
        ob[(size_t)row * (NH * DH) + h * DH + ds * 16 + ll] = f2bf(of[ds][r] * invr[r]);
      }
    __syncthreads();
  }
}

// ---------------------------------------------------------------- launch
extern "C" void kernel_launch(void* const* d_in, const int* in_sizes, int n_in,
                              void* d_out, int out_size, void* d_ws, size_t ws_size,
                              hipStream_t stream) {
  (void)in_sizes; (void)n_in; (void)out_size; (void)ws_size;
  const float* x    = (const float*)d_in[0];
  const float* Wq   = (const float*)d_in[1];
  const float* bq   = (const float*)d_in[2];
  const float* Wk   = (const float*)d_in[3];
  const float* bk   = (const float*)d_in[4];
  const float* Wv   = (const float*)d_in[5];
  const float* bv   = (const float*)d_in[6];
  const float* Wo   = (const float*)d_in[7];
  const float* cosT = (const float*)d_in[8];
  const float* sinT = (const float*)d_in[9];
  // d_in[10] = attention_mask: unused (causal mask computed arithmetically)

  char* ws = (char*)d_ws;
  size_t off = 0;
  auto alloc = [&](size_t bytes) { void* p = ws + off; off += (bytes + 255) & ~(size_t)255; return p; };
  unsigned short* xb    = (unsigned short*)alloc((size_t)L_SEQ * HID * 2);
  unsigned short* Wqkvt = (unsigned short*)alloc((size_t)NQKV * HID * 2);
  unsigned short* Wot   = (unsigned short*)alloc((size_t)HID * HID * 2);
  unsigned short* qbuf  = (unsigned short*)alloc((size_t)NH * L_SEQ * DH * 2);
  unsigned short* kbuf  = (unsigned short*)alloc((size_t)NKV * L_SEQ * DH * 2);
  unsigned short* vlin  = (unsigned short*)alloc((size_t)NKV * L_SEQ * DH * 2);
  unsigned short* vtb   = (unsigned short*)alloc((size_t)NKV * DH * L_SEQ * 2);
  unsigned short* attno = (unsigned short*)alloc((size_t)L_SEQ * HID * 2);

  cast_bf16_kernel<<<(L_SEQ * HID / 4 + 255) / 256, 256, 0, stream>>>(x, xb, L_SEQ * HID / 4);
  transpose_cast_kernel<<<dim3(HID / 64, HID / 64), 256, 0, stream>>>(Wq, Wqkvt, HID, HID);
  transpose_cast_kernel<<<dim3(256 / 64, HID / 64), 256, 0, stream>>>(Wk, Wqkvt + (size_t)4096 * HID, HID, 256);
  transpose_cast_kernel<<<dim3(256 / 64, HID / 64), 256, 0, stream>>>(Wv, Wqkvt + (size_t)4352 * HID, HID, 256);
  transpose_cast_kernel<<<dim3(HID / 64, HID / 64), 256, 0, stream>>>(Wo, Wot, HID, HID);

  // QKV GEMM with fused bias+RoPE epilogue -> qbuf, kbuf, vlin
  gemm128_kernel<1><<<dim3(NQKV / TBN, L_SEQ / TBM), 256, 0, stream>>>(
      xb, Wqkvt, nullptr, bq, bk, bv, cosT, sinT, qbuf, kbuf, vlin, L_SEQ, NQKV, HID);

  vtrans_kernel<<<dim3(L_SEQ / 64, DH / 64, NKV), 256, 0, stream>>>(vlin, vtb);

  attn_kernel<<<dim3(16, NH), 256, 0, stream>>>(qbuf, kbuf, vtb, attno);

  gemm128_kernel<0><<<dim3(HID / TBN, L_SEQ / TBM), 256, 0, stream>>>(
      attno, Wot, (float*)d_out, nullptr, nullptr, nullptr, nullptr, nullptr,
      nullptr, nullptr, nullptr, L_SEQ, HID, HID);
}